// Round 2
// baseline (244.031 us; speedup 1.0000x reference)
//
#include <hip/hip_runtime.h>
#include <math.h>

#define BB   1024   // batch rows
#define FF   1024   // real features (row FF of weights is the bias row)
#define NOUT 512    // 256 erosion cols | 256 dilation cols
#define NW   256    // cols per weight matrix
#define BT   128    // rows per block tile
#define NT   64     // cols per block tile
#define KT   32     // f per LDS chunk
#define KS   16     // K-split factor
#define CH   (FF / KS)        // 64 f per split
#define NCHUNK (CH / KT)      // 2 chunks

// ---- float atomic max/min via int punning (out must be init'd to -inf/+inf) ----
__device__ __forceinline__ void atomMaxF(float* p, float v) {
    if (v >= 0.0f) atomicMax((int*)p, __float_as_int(v));
    else           atomicMin((unsigned int*)p, __float_as_uint(v));
}
__device__ __forceinline__ void atomMinF(float* p, float v) {
    if (v >= 0.0f) atomicMin((int*)p, __float_as_int(v));
    else           atomicMax((unsigned int*)p, __float_as_uint(v));
}

__global__ __launch_bounds__(256) void trop_init(float* __restrict__ out) {
    const int i4 = blockIdx.x * 256 + threadIdx.x;       // float4 index, 131072 total
    const int col = (i4 << 2) & (NOUT - 1);
    const float v = (col < NW) ? INFINITY : -INFINITY;   // ero cols need +inf, dil -inf
    float4 o; o.x = v; o.y = v; o.z = v; o.w = v;
    ((float4*)out)[i4] = o;
}

// IS_ERO: acc = max_f(e[f]-x[f]) over this K slice; final candidate = -acc -> atomMin.
// else:   acc = max_f(x[f]+d[f]);                     final candidate =  acc -> atomMax.
template <bool IS_ERO>
__global__ __launch_bounds__(256, 4) void trop_main(
    const float* __restrict__ x,
    const float* __restrict__ w,
    float* __restrict__ out)
{
    const int bx = blockIdx.x;          // 0..3 col tile within this weight matrix
    const int by = blockIdx.y;          // 0..7 row tile
    const int bz = blockIdx.z;          // 0..KS-1
    const int c0w = bx * NT;            // col offset inside weight matrix
    const int r0 = by * BT;

    __shared__ float lds_x[KT][BT];     // x^T
    __shared__ float lds_w[KT][NT];

    const int tid = threadIdx.x;
    const int cg = tid & 7;             // 8 col groups x 8 cols
    const int rg = tid >> 3;            // 32 row groups x 4 rows

    float acc[4][8];
#pragma unroll
    for (int i = 0; i < 4; ++i)
#pragma unroll
        for (int j = 0; j < 8; ++j) acc[i][j] = -INFINITY;

    const int fstart = bz * CH;

#pragma unroll
    for (int kc = 0; kc < NCHUNK; ++kc) {
        const int fb = fstart + kc * KT;

        // ---- stage x^T (128 rows x 32 f) ----
#pragma unroll
        for (int it = 0; it < 4; ++it) {
            const int tt = tid + it * 256;
            const int r = tt & 127;
            const int g = tt >> 7;      // 0..7 -> f group of 4
            const float4 v = *(const float4*)(x + (size_t)(r0 + r) * FF + fb + g * 4);
            lds_x[g * 4 + 0][r] = v.x;
            lds_x[g * 4 + 1][r] = v.y;
            lds_x[g * 4 + 2][r] = v.z;
            lds_x[g * 4 + 3][r] = v.w;
        }
        // ---- stage w (32 f x 64 cols), natural layout ----
#pragma unroll
        for (int it = 0; it < 2; ++it) {
            const int tt = tid + it * 256;
            const int f = tt >> 4;      // 0..31
            const int c4 = tt & 15;     // 0..15
            *(float4*)&lds_w[f][c4 * 4] =
                *(const float4*)(w + (size_t)(fb + f) * NW + c0w + c4 * 4);
        }
        __syncthreads();

        // ---- max-plus / max-minus inner loop, K-unrolled by 2 for v_max3 ----
#pragma unroll
        for (int ff = 0; ff < KT; ff += 2) {
            const float4 x0 = *(const float4*)&lds_x[ff][rg << 2];
            const float4 x1 = *(const float4*)&lds_x[ff + 1][rg << 2];
            const float4 wa0 = *(const float4*)&lds_w[ff][cg << 3];
            const float4 wb0 = *(const float4*)&lds_w[ff][(cg << 3) + 4];
            const float4 wa1 = *(const float4*)&lds_w[ff + 1][cg << 3];
            const float4 wb1 = *(const float4*)&lds_w[ff + 1][(cg << 3) + 4];
            const float xr0[4] = {x0.x, x0.y, x0.z, x0.w};
            const float xr1[4] = {x1.x, x1.y, x1.z, x1.w};
            const float wc0[8] = {wa0.x, wa0.y, wa0.z, wa0.w, wb0.x, wb0.y, wb0.z, wb0.w};
            const float wc1[8] = {wa1.x, wa1.y, wa1.z, wa1.w, wb1.x, wb1.y, wb1.z, wb1.w};
#pragma unroll
            for (int i = 0; i < 4; ++i)
#pragma unroll
                for (int j = 0; j < 8; ++j) {
                    if (IS_ERO)
                        acc[i][j] = fmaxf(acc[i][j],
                                          fmaxf(wc0[j] - xr0[i], wc1[j] - xr1[i]));
                    else
                        acc[i][j] = fmaxf(acc[i][j],
                                          fmaxf(xr0[i] + wc0[j], xr1[i] + wc1[j]));
                }
        }
        __syncthreads();
    }

    // ---- bias row f=FF (x contribution 0): candidate is w_bias in max-form ----
    if (bz == KS - 1) {
        const float4 ba = *(const float4*)(w + (size_t)FF * NW + c0w + (cg << 3));
        const float4 bb = *(const float4*)(w + (size_t)FF * NW + c0w + (cg << 3) + 4);
        const float bc[8] = {ba.x, ba.y, ba.z, ba.w, bb.x, bb.y, bb.z, bb.w};
#pragma unroll
        for (int i = 0; i < 4; ++i)
#pragma unroll
            for (int j = 0; j < 8; ++j) acc[i][j] = fmaxf(acc[i][j], bc[j]);
    }

    // ---- merge K-split partials with fire-and-forget float atomics ----
    const int cglob = (IS_ERO ? 0 : NW) + c0w + (cg << 3);
#pragma unroll
    for (int i = 0; i < 4; ++i) {
        const int row = r0 + (rg << 2) + i;
        float* p = out + (size_t)row * NOUT + cglob;
#pragma unroll
        for (int j = 0; j < 8; ++j) {
            if (IS_ERO) atomMinF(p + j, -acc[i][j]);
            else        atomMaxF(p + j,  acc[i][j]);
        }
    }
}

extern "C" void kernel_launch(void* const* d_in, const int* in_sizes, int n_in,
                              void* d_out, int out_size, void* d_ws, size_t ws_size,
                              hipStream_t stream) {
    const float* x = (const float*)d_in[0];
    const float* dil = (const float*)d_in[1];
    const float* ero = (const float*)d_in[2];
    float* out = (float*)d_out;

    trop_init<<<BB * NOUT / 4 / 256, 256, 0, stream>>>(out);

    dim3 grid(NW / NT, BB / BT, KS);   // (4, 8, 16) = 512 blocks each
    trop_main<true ><<<grid, 256, 0, stream>>>(x, ero, out);
    trop_main<false><<<grid, 256, 0, stream>>>(x, dil, out);
}

// Round 3
// 92.347 us; speedup vs baseline: 2.6425x; 2.6425x over previous
//
#include <hip/hip_runtime.h>
#include <math.h>

#define BB   1024   // batch rows
#define FF   1024   // real features (row FF of weights is the bias row)
#define NOUT 512    // output cols: [0,256)=eroded, [256,512)=dilated
#define NW   256    // cols per weight matrix
#define BT   128    // rows per block tile
#define CT   128    // cols per block tile
#define KT   64     // f per block (single chunk)
#define KS   (FF / KT)   // 16 K-split planes

// Block: 256 threads = 16 col-groups (cg) x 16 row-groups (rg).
// Thread tile: 8 rows (rg*8..+7) x 8 cols (cg*4..+3 and 64+cg*4..+3).
// Erosion unified into max-plus: stage -x, so acc = max_f(w - x); store -acc.
__global__ __launch_bounds__(256, 2) void trop_main(
    const float* __restrict__ x,
    const float* __restrict__ dil,
    const float* __restrict__ ero,
    float* __restrict__ ws)
{
    const int bx = blockIdx.x;          // 0,1: erosion col tiles; 2,3: dilation
    const int by = blockIdx.y;          // 0..7 row tile
    const int bz = blockIdx.z;          // 0..KS-1 f slice
    const bool is_ero = (bx < 2);
    const float* __restrict__ w = is_ero ? ero : dil;
    const int c0w = (bx & 1) * CT;      // col offset inside weight matrix
    const int r0 = by * BT;
    const float sgn = is_ero ? -1.0f : 1.0f;
    const int fb = bz * KT;

    __shared__ float lds_x[KT][BT];     // x^T, sign-applied, XOR-swizzled 8-row blocks
    __shared__ float lds_w[KT][CT];     // natural layout

    const int tid = threadIdx.x;
    const int cg = tid & 15;
    const int rg = tid >> 4;

    // ---- stage x^T (128 rows x 64 f), sign applied, swizzled ----
#pragma unroll
    for (int it = 0; it < 8; ++it) {
        const int idx = it * 256 + tid;
        const int r = idx >> 4;         // 0..127
        const int g = idx & 15;         // f group of 4 (coalesced 16B per lane)
        const float4 v = *(const float4*)(x + (size_t)(r0 + r) * FF + fb + g * 4);
        const int rb = r >> 3, rl = r & 7;
        const float vv[4] = {v.x, v.y, v.z, v.w};
#pragma unroll
        for (int q = 0; q < 4; ++q) {
            const int f = g * 4 + q;
            lds_x[f][((rb ^ (f & 15)) << 3) | rl] = sgn * vv[q];
        }
    }
    // ---- stage w (64 f x 128 cols) ----
#pragma unroll
    for (int it = 0; it < 8; ++it) {
        const int idx = it * 256 + tid;
        const int f = idx >> 5;         // 0..63
        const int c4 = idx & 31;        // 0..31
        *(float4*)&lds_w[f][c4 * 4] =
            *(const float4*)(w + (size_t)(fb + f) * NW + c0w + c4 * 4);
    }
    __syncthreads();

    float acc[8][8];
#pragma unroll
    for (int i = 0; i < 8; ++i)
#pragma unroll
        for (int j = 0; j < 8; ++j) acc[i][j] = -INFINITY;

    // ---- max-plus inner loop over 64 f, paired for v_max3 fusion ----
#pragma unroll 2
    for (int ff = 0; ff < KT; ff += 2) {
        const int s0 = ((rg ^ (ff & 15)) << 3);
        const int s1 = ((rg ^ ((ff + 1) & 15)) << 3);
        const float4 xa0 = *(const float4*)&lds_x[ff][s0];
        const float4 xb0 = *(const float4*)&lds_x[ff][s0 + 4];
        const float4 xa1 = *(const float4*)&lds_x[ff + 1][s1];
        const float4 xb1 = *(const float4*)&lds_x[ff + 1][s1 + 4];
        const float4 wa0 = *(const float4*)&lds_w[ff][cg * 4];
        const float4 wb0 = *(const float4*)&lds_w[ff][64 + cg * 4];
        const float4 wa1 = *(const float4*)&lds_w[ff + 1][cg * 4];
        const float4 wb1 = *(const float4*)&lds_w[ff + 1][64 + cg * 4];
        const float xr0[8] = {xa0.x, xa0.y, xa0.z, xa0.w, xb0.x, xb0.y, xb0.z, xb0.w};
        const float xr1[8] = {xa1.x, xa1.y, xa1.z, xa1.w, xb1.x, xb1.y, xb1.z, xb1.w};
        const float wc0[8] = {wa0.x, wa0.y, wa0.z, wa0.w, wb0.x, wb0.y, wb0.z, wb0.w};
        const float wc1[8] = {wa1.x, wa1.y, wa1.z, wa1.w, wb1.x, wb1.y, wb1.z, wb1.w};
#pragma unroll
        for (int i = 0; i < 8; ++i)
#pragma unroll
            for (int j = 0; j < 8; ++j) {
                acc[i][j] = fmaxf(acc[i][j],
                                  fmaxf(xr0[i] + wc0[j], xr1[i] + wc1[j]));
            }
    }

    // ---- bias row f=FF (x contribution 0 in max-form for both operators) ----
    if (bz == KS - 1) {
        const float4 ba = *(const float4*)(w + (size_t)FF * NW + c0w + cg * 4);
        const float4 bb = *(const float4*)(w + (size_t)FF * NW + c0w + 64 + cg * 4);
        const float bc[8] = {ba.x, ba.y, ba.z, ba.w, bb.x, bb.y, bb.z, bb.w};
#pragma unroll
        for (int i = 0; i < 8; ++i)
#pragma unroll
            for (int j = 0; j < 8; ++j) acc[i][j] = fmaxf(acc[i][j], bc[j]);
    }

    // ---- store partial plane (undo sign for erosion -> min-form partial) ----
    float* plane = ws + (size_t)bz * (BB * NOUT);
    const int cglob = bx * CT + cg * 4;   // bx*128 maps ero->0..255, dil->256..511
#pragma unroll
    for (int i = 0; i < 8; ++i) {
        const int row = r0 + rg * 8 + i;
        float4 v0, v1;
        v0.x = sgn * acc[i][0]; v0.y = sgn * acc[i][1];
        v0.z = sgn * acc[i][2]; v0.w = sgn * acc[i][3];
        v1.x = sgn * acc[i][4]; v1.y = sgn * acc[i][5];
        v1.z = sgn * acc[i][6]; v1.w = sgn * acc[i][7];
        *(float4*)(plane + (size_t)row * NOUT + cglob) = v0;
        *(float4*)(plane + (size_t)row * NOUT + cglob + 64) = v1;
    }
}

// combine KS partial planes: min for erosion cols (<256), max for dilation cols
__global__ __launch_bounds__(256) void trop_combine(
    const float* __restrict__ ws, float* __restrict__ out)
{
    const int i4 = blockIdx.x * 256 + threadIdx.x;   // float4 index over [BB][NOUT/4]
    const bool ero = (i4 & 127) < 64;
    const int stride4 = BB * NOUT / 4;
    float4 v = ((const float4*)ws)[i4];
#pragma unroll
    for (int z = 1; z < KS; ++z) {
        const float4 u = ((const float4*)ws)[(size_t)z * stride4 + i4];
        if (ero) {
            v.x = fminf(v.x, u.x); v.y = fminf(v.y, u.y);
            v.z = fminf(v.z, u.z); v.w = fminf(v.w, u.w);
        } else {
            v.x = fmaxf(v.x, u.x); v.y = fmaxf(v.y, u.y);
            v.z = fmaxf(v.z, u.z); v.w = fmaxf(v.w, u.w);
        }
    }
    ((float4*)out)[i4] = v;
}

extern "C" void kernel_launch(void* const* d_in, const int* in_sizes, int n_in,
                              void* d_out, int out_size, void* d_ws, size_t ws_size,
                              hipStream_t stream) {
    const float* x = (const float*)d_in[0];
    const float* dil = (const float*)d_in[1];
    const float* ero = (const float*)d_in[2];
    float* out = (float*)d_out;
    float* ws = (float*)d_ws;

    dim3 grid(4, BB / BT, KS);   // 4 col tiles x 8 row tiles x 16 f slices = 512 blocks
    trop_main<<<grid, 256, 0, stream>>>(x, dil, ero, ws);
    trop_combine<<<BB * NOUT / 4 / 256, 256, 0, stream>>>(ws, out);
}